// Round 5
// baseline (271.990 us; speedup 1.0000x reference)
//
#include <hip/hip_runtime.h>
#include <cstdint>

#define DEV static __device__ __forceinline__

typedef __attribute__((ext_vector_type(8))) short bf16x8;   // 8 bf16 = 4 VGPRs
typedef __attribute__((ext_vector_type(4))) short bf16x4v;  // 4 bf16
typedef __attribute__((ext_vector_type(4))) float f32x4;

DEV float bf2f(short s) {
  union { unsigned u; float f; } c; c.u = ((unsigned)(unsigned short)s) << 16; return c.f;
}
DEV short f2bf(float f) {  // round-to-nearest-even
  union { float f; unsigned u; } c; c.f = f;
  unsigned r = c.u + 0x7FFF + ((c.u >> 16) & 1);
  return (short)(r >> 16);
}
// async global->LDS DMA, 16B per lane. HW: wave-uniform LDS base + lane*16;
// per-lane global source. Our per-lane lds addr includes +lane*16 so lane0's
// value IS the base (m97 pattern).
DEV void g2lds16(const void* g, void* l) {
  __builtin_amdgcn_global_load_lds(
      (const __attribute__((address_space(1))) void*)g,
      (__attribute__((address_space(3))) void*)l, 16, 0, 0);
}

// ---------------- prep: f32->bf16 convert + weight transpose, one launch ----
// blocks [0,8192): convert s1,s2 (float4 -> bf16x4 each thread)
// blocks [8192,12288): 32x32 tile transpose+convert of Wq/Wk/Wv/Wo
__global__ __launch_bounds__(256) void prep_kernel(
    const float* __restrict__ s1, short* __restrict__ s1b,
    const float* __restrict__ s2, short* __restrict__ s2b,
    const float* __restrict__ w0, short* __restrict__ t0,
    const float* __restrict__ w1, short* __restrict__ t1,
    const float* __restrict__ w2, short* __restrict__ t2,
    const float* __restrict__ w3, short* __restrict__ t3) {
  __shared__ float tile[32][33];
  const int bid = blockIdx.x, tid = threadIdx.x;
  if (bid < 8192) {
    int i = bid * 256 + tid;
    const float* in = s1; short* out = s1b;
    if (i >= 1048576) { i -= 1048576; in = s2; out = s2b; }
    float4 v = reinterpret_cast<const float4*>(in)[i];
    bf16x4v o; o[0] = f2bf(v.x); o[1] = f2bf(v.y); o[2] = f2bf(v.z); o[3] = f2bf(v.w);
    reinterpret_cast<bf16x4v*>(out)[i] = o;
  } else {
    int b2 = bid - 8192;
    int z = b2 >> 10, rem = b2 & 1023;
    int bx = rem & 31, by = rem >> 5;
    int tx = tid & 31, ty = tid >> 5;           // 32 x 8
    const float* W; short* Wt;
    switch (z) {
      case 0: W = w0; Wt = t0; break;
      case 1: W = w1; Wt = t1; break;
      case 2: W = w2; Wt = t2; break;
      default: W = w3; Wt = t3; break;
    }
#pragma unroll
    for (int j = 0; j < 4; ++j)
      tile[ty + 8 * j][tx] = W[(size_t)(by * 32 + ty + 8 * j) * 1024 + bx * 32 + tx];
    __syncthreads();
#pragma unroll
    for (int j = 0; j < 4; ++j)
      Wt[(size_t)(bx * 32 + ty + 8 * j) * 1024 + by * 32 + tx] = f2bf(tile[tx][ty + 8 * j]);
  }
}

// ---------------- shared GEMM core: m97-verified 128x128x64 structure -------
// C[m0+128][n0+128] = A[.][1024] * Bt[.][1024]^T. 4 waves (2m x 2n), each
// wave 64x64 output = 4x4 16x16x32 frags. K = 1024 (16 kt steps).
// Epilogue lambda receives (m, n, raw_acc) — bias handled by caller.
template <typename EPI>
DEV void gemm_core128(const short* __restrict__ A, const short* __restrict__ Bt,
                      int m0, int n0, EPI epi) {
  __shared__ alignas(16) short As[128 * 64];   // [m-local][k] linear (g2lds dest)
  __shared__ alignas(16) short Bs[128 * 64];   // [n-local][k] linear
  const int tid = threadIdx.x, lane = tid & 63, w = tid >> 6;
  const int wm = (w >> 1) * 64, wn = (w & 1) * 64;

  f32x4 acc[4][4] = {};

  for (int kt = 0; kt < 16; ++kt) {
    __syncthreads();   // prev iter's frag reads done
#pragma unroll
    for (int rnd = 0; rnd < 4; ++rnd) {      // A: 128 rows x 64 k
      int c = tid + rnd * 256;
      int row = c >> 3, ch = c & 7;
      g2lds16(A + (size_t)(m0 + row) * 1024 + kt * 64 + ch * 8, (char*)As + c * 16);
    }
#pragma unroll
    for (int rnd = 0; rnd < 4; ++rnd) {      // B: 128 rows x 64 k
      int c = tid + rnd * 256;
      int row = c >> 3, ch = c & 7;
      g2lds16(Bt + (size_t)(n0 + row) * 1024 + kt * 64 + ch * 8, (char*)Bs + c * 16);
    }
    asm volatile("s_waitcnt vmcnt(0)" ::: "memory");
    __syncthreads();
#pragma unroll
    for (int kk = 0; kk < 64; kk += 32) {
      bf16x8 a[4], b[4];
#pragma unroll
      for (int i = 0; i < 4; ++i)
        a[i] = *reinterpret_cast<const bf16x8*>(&As[(wm + i * 16 + (lane & 15)) * 64 + kk + 8 * (lane >> 4)]);
#pragma unroll
      for (int i = 0; i < 4; ++i)
        b[i] = *reinterpret_cast<const bf16x8*>(&Bs[(wn + i * 16 + (lane & 15)) * 64 + kk + 8 * (lane >> 4)]);
#pragma unroll
      for (int mi = 0; mi < 4; ++mi)
#pragma unroll
        for (int ni = 0; ni < 4; ++ni)
          acc[mi][ni] = __builtin_amdgcn_mfma_f32_16x16x32_bf16(a[mi], b[ni], acc[mi][ni], 0, 0, 0);
    }
  }
  // D layout (m89-verified): row = 4*(lane>>4)+r, col = lane&15
#pragma unroll
  for (int mi = 0; mi < 4; ++mi)
#pragma unroll
    for (int ni = 0; ni < 4; ++ni)
#pragma unroll
      for (int r = 0; r < 4; ++r) {
        int m = m0 + wm + mi * 16 + 4 * (lane >> 4) + r;
        int n = n0 + wn + ni * 16 + (lane & 15);
        epi(m, n, acc[mi][ni][r]);
      }
}

// merged Q/K/V projections. z=0: Q = s1*WqT -> [B][H][S][HD]; z=1: K likewise;
// z=2: Vt computed TRANSPOSED via operand swap: C'[d][s] = WvT[d][k]*s2[s][k]
// -> [B][H][HD][S] with contiguous stores. 256 blocks per slice, XCD-swizzled
// so each XCD owns 4 contiguous panel-rows (A reuse / s2 reuse).
__global__ __launch_bounds__(256) void qkv_gemm_kernel(
    const short* __restrict__ s1b, const short* __restrict__ s2b,
    const short* __restrict__ wqt, const short* __restrict__ wkt,
    const short* __restrict__ wvt,
    const float* __restrict__ bq, const float* __restrict__ bk,
    const float* __restrict__ bv,
    short* __restrict__ qb, short* __restrict__ kb, short* __restrict__ vtb) {
  const int z = blockIdx.z;
  int flat = blockIdx.y * 8 + blockIdx.x;       // 256 blocks/slice, %8==0
  int r8 = flat & 7, q8 = flat >> 3;
  int lg = r8 * 32 + q8;                        // XCD r8 gets lg in [32*r8, 32*r8+32)
  if (z < 2) {
    const short* A = (z == 0) ? s1b : s2b;
    const short* Bt = (z == 0) ? wqt : wkt;
    const float* bias = (z == 0) ? bq : bk;
    short* out = (z == 0) ? qb : kb;
    int n0 = (lg & 7) * 128, m0 = (lg >> 3) * 128;  // m over 4096 (seq), n over 1024
    gemm_core128(A, Bt, m0, n0, [&](int m, int n, float v) {
      v += bias[n];  // n = feature dim
      out[(((size_t)(m >> 9) * 16 + (n >> 6)) * 512 + (m & 511)) * 64 + (n & 63)] = f2bf(v);
    });
  } else {
    int m0 = (lg & 7) * 128, n0 = (lg >> 3) * 128;  // m over 1024 (d), n over 4096 (s)
    gemm_core128(wvt, s2b, m0, n0, [&](int m, int n, float v) {
      v += bv[m];    // m = feature dim (d)
      vtb[(((size_t)(n >> 9) * 16 + (m >> 6)) * 64 + (m & 63)) * 512 + (n & 511)] = f2bf(v);
    });
  }
}

// Wo projection + bias + s1 residual, f32 row-major output
__global__ __launch_bounds__(256) void wo_gemm_kernel(
    const short* __restrict__ A, const short* __restrict__ Bt,
    const float* __restrict__ bias, const float* __restrict__ s1,
    float* __restrict__ out) {
  int flat = blockIdx.y * 8 + blockIdx.x;       // 256 blocks
  int r8 = flat & 7, q8 = flat >> 3;
  int lg = r8 * 32 + q8;
  int n0 = (lg & 7) * 128, m0 = (lg >> 3) * 128;
  gemm_core128(A, Bt, m0, n0, [&](int m, int n, float v) {
    out[(size_t)m * 1024 + n] = v + bias[n] + s1[(size_t)m * 1024 + n];
  });
}

// ---------------- fused attention: barrier-free, staging-free ---------------
// grid (8,128) XCD-swizzled (16 bh per XCD -> K/V tiles L2-resident, 8x reuse),
// 256 threads = 4 waves. Wave w owns q-rows [16w,16w+16) for ALL phases; the
// only LDS is the per-wave-partitioned score/prob buffer -> ZERO __syncthreads.
// Phase 1 computes mfma(K, Q) (swapped operands): C row = k-local (4*l4+r),
// col = q-local (l15) -> each lane writes 4 CONSECUTIVE k of one q-row as a
// single packed ds_write_b64, and mask loads become aligned float4.
__global__ __launch_bounds__(256) void attn_kernel(
    const short* __restrict__ Qg, const short* __restrict__ Kg,
    const short* __restrict__ Vtg, const float* __restrict__ maskg,
    const int* __restrict__ clp, short* __restrict__ ctx) {
  __shared__ alignas(16) short Sv[64 * 520];  // scores -> P, in place (65 KB)

  const int tid = threadIdx.x, lane = tid & 63, w = tid >> 6;
  const int l15 = lane & 15, l4 = lane >> 4;
  int flat = blockIdx.y * 8 + blockIdx.x;     // 1024 blocks
  int r8 = flat & 7, q8 = flat >> 3;
  int lg = r8 * 128 + q8;                     // XCD r8: bh in [16*r8, 16*r8+16)
  const int qt = lg & 7, bh = lg >> 3, b = bh >> 4;
  const int cl = clp[0];
  const float* mrow = maskg + b * 512;

  // Q fragments straight to registers ([bh][s][64] row-major)
  const short* qbase = Qg + ((size_t)bh * 512 + qt * 64 + w * 16 + l15) * 64 + 8 * l4;
  bf16x8 qf0 = *reinterpret_cast<const bf16x8*>(qbase);
  bf16x8 qf1 = *reinterpret_cast<const bf16x8*>(qbase + 32);

  // phase 1: Sv[q][k] = K Q^T / 8 + mask (swapped operands, packed b64 writes)
  const short* kbh = Kg + (size_t)bh * 512 * 64 + 8 * l4;
  short* qrow = &Sv[(w * 16 + l15) * 520];    // this lane's q-row
  for (int kt = 0; kt < 8; ++kt) {
#pragma unroll
    for (int ni = 0; ni < 4; ++ni) {
      const short* kp = kbh + (size_t)(kt * 64 + ni * 16 + l15) * 64;
      bf16x8 k0 = *reinterpret_cast<const bf16x8*>(kp);
      bf16x8 k1 = *reinterpret_cast<const bf16x8*>(kp + 32);
      f32x4 acc = {};
      __builtin_amdgcn_s_setprio(1);
      acc = __builtin_amdgcn_mfma_f32_16x16x32_bf16(k0, qf0, acc, 0, 0, 0);
      acc = __builtin_amdgcn_mfma_f32_16x16x32_bf16(k1, qf1, acc, 0, 0, 0);
      __builtin_amdgcn_s_setprio(0);
      int kb4 = kt * 64 + ni * 16 + 4 * l4;   // 4 consecutive k for q-row l15
      f32x4 mk = *reinterpret_cast<const f32x4*>(&mrow[kb4]);
      bf16x4v pk;
#pragma unroll
      for (int r = 0; r < 4; ++r) pk[r] = f2bf(acc[r] * 0.125f + mk[r]);
      *reinterpret_cast<bf16x4v*>(&qrow[kb4]) = pk;
    }
  }

  // phase 2: double softmax, in place. 4 lanes/row, row = tid>>2 (own wave's).
  const int row = tid >> 2, sub = tid & 3;
  short* prow = &Sv[row * 520];
  float m1 = -1e30f;
#pragma unroll 4
  for (int j = 0; j < 16; ++j) {
    bf16x8 v = *reinterpret_cast<const bf16x8*>(&prow[(4 * j + sub) * 8]);
#pragma unroll
    for (int t = 0; t < 8; ++t) m1 = fmaxf(m1, bf2f(v[t]));
  }
  m1 = fmaxf(m1, __shfl_xor(m1, 1, 4));
  m1 = fmaxf(m1, __shfl_xor(m1, 2, 4));
  float Z1 = 0.f;
#pragma unroll 4
  for (int j = 0; j < 16; ++j) {
    int c0 = (4 * j + sub) * 8;
    bf16x8 v = *reinterpret_cast<const bf16x8*>(&prow[c0]);
    bf16x8 o;
#pragma unroll
    for (int t = 0; t < 8; ++t) {
      float e = __expf(bf2f(v[t]) - m1);
      Z1 += e; o[t] = f2bf(e);
    }
    *reinterpret_cast<bf16x8*>(&prow[c0]) = o;
  }
  Z1 += __shfl_xor(Z1, 1, 4); Z1 += __shfl_xor(Z1, 2, 4);
  float rZ1 = 1.0f / Z1;

  float rowscale;
  if (cl) {  // softmax(1 - p + mask): p = e/Z1, P now holds e
    float m2 = -1e30f;
#pragma unroll 4
    for (int j = 0; j < 16; ++j) {
      int c0 = (4 * j + sub) * 8;
      bf16x8 v = *reinterpret_cast<const bf16x8*>(&prow[c0]);
      f32x4 ma = *reinterpret_cast<const f32x4*>(&mrow[c0]);
      f32x4 mb = *reinterpret_cast<const f32x4*>(&mrow[c0 + 4]);
#pragma unroll
      for (int t = 0; t < 8; ++t) {
        float msk = (t < 4) ? ma[t] : mb[t - 4];
        m2 = fmaxf(m2, 1.0f - bf2f(v[t]) * rZ1 + msk);
      }
    }
    m2 = fmaxf(m2, __shfl_xor(m2, 1, 4));
    m2 = fmaxf(m2, __shfl_xor(m2, 2, 4));
    float Z2 = 0.f;
#pragma unroll 4
    for (int j = 0; j < 16; ++j) {
      int c0 = (4 * j + sub) * 8;
      bf16x8 v = *reinterpret_cast<const bf16x8*>(&prow[c0]);
      f32x4 ma = *reinterpret_cast<const f32x4*>(&mrow[c0]);
      f32x4 mb = *reinterpret_cast<const f32x4*>(&mrow[c0 + 4]);
      bf16x8 o;
#pragma unroll
      for (int t = 0; t < 8; ++t) {
        float msk = (t < 4) ? ma[t] : mb[t - 4];
        float e = __expf(1.0f - bf2f(v[t]) * rZ1 + msk - m2);
        Z2 += e; o[t] = f2bf(e);
      }
      *reinterpret_cast<bf16x8*>(&prow[c0]) = o;
    }
    Z2 += __shfl_xor(Z2, 1, 4); Z2 += __shfl_xor(Z2, 2, 4);
    rowscale = 1.0f / Z2;
  } else {
    rowscale = rZ1;  // P holds unnormalized e; fold 1/Z into epilogue
  }

  // phase 3: ctx = P @ V. A = own wave's P rows (LDS), B = Vt from global.
  f32x4 o[4] = {};
  const short* vbh = Vtg + (size_t)bh * 64 * 512 + 8 * l4;
  for (int kc = 0; kc < 16; ++kc) {
    bf16x8 a = *reinterpret_cast<const bf16x8*>(&Sv[(w * 16 + l15) * 520 + kc * 32 + 8 * l4]);
    bf16x8 bfr0 = *reinterpret_cast<const bf16x8*>(vbh + (size_t)(0 * 16 + l15) * 512 + kc * 32);
    bf16x8 bfr1 = *reinterpret_cast<const bf16x8*>(vbh + (size_t)(1 * 16 + l15) * 512 + kc * 32);
    bf16x8 bfr2 = *reinterpret_cast<const bf16x8*>(vbh + (size_t)(2 * 16 + l15) * 512 + kc * 32);
    bf16x8 bfr3 = *reinterpret_cast<const bf16x8*>(vbh + (size_t)(3 * 16 + l15) * 512 + kc * 32);
    __builtin_amdgcn_s_setprio(1);
    o[0] = __builtin_amdgcn_mfma_f32_16x16x32_bf16(a, bfr0, o[0], 0, 0, 0);
    o[1] = __builtin_amdgcn_mfma_f32_16x16x32_bf16(a, bfr1, o[1], 0, 0, 0);
    o[2] = __builtin_amdgcn_mfma_f32_16x16x32_bf16(a, bfr2, o[2], 0, 0, 0);
    o[3] = __builtin_amdgcn_mfma_f32_16x16x32_bf16(a, bfr3, o[3], 0, 0, 0);
    __builtin_amdgcn_s_setprio(0);
  }
  // per-row 1/Z via intra-wave shuffle (rowscale lives in lanes 4*row_local+sub)
  float sc[4];
#pragma unroll
  for (int r = 0; r < 4; ++r) sc[r] = __shfl(rowscale, 16 * l4 + 4 * r, 64);
  const int h = bh & 15;
#pragma unroll
  for (int ni = 0; ni < 4; ++ni)
#pragma unroll
    for (int r = 0; r < 4; ++r) {
      int s = qt * 64 + w * 16 + 4 * l4 + r;
      int d = ni * 16 + l15;
      ctx[((size_t)b * 512 + s) * 1024 + h * 64 + d] = f2bf(o[ni][r] * sc[r]);
    }
}

// ---------------- LayerNorm (input already h + bias + s1) -------------------
__global__ __launch_bounds__(256) void ln_kernel(
    const float* __restrict__ hbuf,
    const float* __restrict__ lw, const float* __restrict__ lb,
    float* __restrict__ out) {
  __shared__ float red[8];
  const int row = blockIdx.x, tid = threadIdx.x;
  float4 hv = reinterpret_cast<const float4*>(hbuf + (size_t)row * 1024)[tid];
  float x0 = hv.x, x1 = hv.y, x2 = hv.z, x3 = hv.w;
  float s = x0 + x1 + x2 + x3;
  float ss = x0 * x0 + x1 * x1 + x2 * x2 + x3 * x3;
  for (int o = 32; o; o >>= 1) { s += __shfl_down(s, o); ss += __shfl_down(ss, o); }
  int w = tid >> 6;
  if ((tid & 63) == 0) { red[w] = s; red[4 + w] = ss; }
  __syncthreads();
  float S = red[0] + red[1] + red[2] + red[3];
  float SS = red[4] + red[5] + red[6] + red[7];
  float u = S * (1.f / 1024.f);
  float var = SS * (1.f / 1024.f) - u * u;
  float inv = rsqrtf(var + 1e-12f);
  float4 wv = reinterpret_cast<const float4*>(lw)[tid];
  float4 bv = reinterpret_cast<const float4*>(lb)[tid];
  float4 ov;
  ov.x = wv.x * (x0 - u) * inv + bv.x;
  ov.y = wv.y * (x1 - u) * inv + bv.y;
  ov.z = wv.z * (x2 - u) * inv + bv.z;
  ov.w = wv.w * (x3 - u) * inv + bv.w;
  reinterpret_cast<float4*>(out + (size_t)row * 1024)[tid] = ov;
}

// ---------------- launcher ---------------------------------------------------
extern "C" void kernel_launch(void* const* d_in, const int* in_sizes, int n_in,
                              void* d_out, int out_size, void* d_ws, size_t ws_size,
                              hipStream_t stream) {
  const float* s1 = (const float*)d_in[0];
  const float* s2 = (const float*)d_in[1];
  const float* mask = (const float*)d_in[2];
  const float* Wq = (const float*)d_in[3]; const float* bq = (const float*)d_in[4];
  const float* Wk = (const float*)d_in[5]; const float* bk = (const float*)d_in[6];
  const float* Wv = (const float*)d_in[7]; const float* bv = (const float*)d_in[8];
  const float* Wo = (const float*)d_in[9]; const float* bo = (const float*)d_in[10];
  const float* lnw = (const float*)d_in[11]; const float* lnb = (const float*)d_in[12];
  const int* cl = (const int*)d_in[13];
  float* out = (float*)d_out;

  char* ws = (char*)d_ws;
  short* s1b = (short*)ws; ws += (size_t)4096 * 1024 * 2;
  short* s2b = (short*)ws; ws += (size_t)4096 * 1024 * 2;
  short* wqt = (short*)ws; ws += (size_t)1024 * 1024 * 2;
  short* wkt = (short*)ws; ws += (size_t)1024 * 1024 * 2;
  short* wvt = (short*)ws; ws += (size_t)1024 * 1024 * 2;
  short* wot = (short*)ws; ws += (size_t)1024 * 1024 * 2;
  short* qb  = (short*)ws; ws += (size_t)4096 * 1024 * 2;
  short* kb  = (short*)ws; ws += (size_t)4096 * 1024 * 2;
  short* vtb = (short*)ws; ws += (size_t)4096 * 1024 * 2;
  short* ctxb= (short*)ws; ws += (size_t)4096 * 1024 * 2;
  float* hb  = (float*)ws; ws += (size_t)4096 * 1024 * 4;

  prep_kernel<<<12288, 256, 0, stream>>>(s1, s1b, s2, s2b,
                                         Wq, wqt, Wk, wkt, Wv, wvt, Wo, wot);
  qkv_gemm_kernel<<<dim3(8, 32, 3), 256, 0, stream>>>(s1b, s2b, wqt, wkt, wvt,
                                                      bq, bk, bv, qb, kb, vtb);
  attn_kernel<<<dim3(8, 128), 256, 0, stream>>>(qb, kb, vtb, mask, cl, ctxb);
  wo_gemm_kernel<<<dim3(8, 32), 256, 0, stream>>>(ctxb, wot, bo, s1, hb);
  ln_kernel<<<4096, 256, 0, stream>>>(hb, lnw, lnb, out);
}